// Round 4
// baseline (917.954 us; speedup 1.0000x reference)
//
#include <hip/hip_runtime.h>
#include <math.h>

constexpr int kE = 32;    // experts
constexpr int kH = 2048;  // hidden
constexpr int kI = 768;   // expert intermediate dim
constexpr int kT = 2048;  // tokens
constexpr int kK = 4;     // top-k
constexpr int kTM = 320;  // token tile (covers max Ne in one pass; loop if not)

typedef _Float16 half8  __attribute__((ext_vector_type(8)));
typedef _Float16 half4v __attribute__((ext_vector_type(4)));
typedef float    float4v __attribute__((ext_vector_type(4)));

// Workspace layout (bytes):
//   [0,256)        expert_offsets int[kE+1]
//   [256,..)       token_ids int[8192]
//   [33024,..)     token_w  float[8192]
//   [65792,..)     inv      int[8192]         (slot id per (t,k), -1 if dup)
//   [98560,..)     gated    _Float16[8192][768]   (~12.6 MB)
//   [12681472,..)  eo       float[8192][2048]     (~67 MB, weighted expert out)
//   [79790336,..)  hs16     _Float16[2048][2048]  (~8.4 MB)
constexpr size_t kOffsOff  = 0;
constexpr size_t kTokOff   = 256;
constexpr size_t kTwOff    = 33024;
constexpr size_t kInvOff   = 65792;
constexpr size_t kGatedOff = 98560;
constexpr size_t kEoOff    = 12681472;
constexpr size_t kHs16Off  = 79790336;

// ---------------------------------------------------------------------------
// Routing. numpy scatter semantics: last duplicate wins, expert contributes
// once. Emits inverse map inv[t*4+k] = slot (or -1 for shadowed duplicates).
// ---------------------------------------------------------------------------
__global__ __launch_bounds__(256) void route_kernel(
    const int* __restrict__ ridx, const float* __restrict__ rw,
    int* __restrict__ offs, int* __restrict__ tok, float* __restrict__ tw,
    int* __restrict__ inv) {
  __shared__ int s_cnt[kE];
  __shared__ int s_off[kE + 1];
  __shared__ int s_cur[kE];
  const int tid = threadIdx.x;
  if (tid < kE) { s_cnt[tid] = 0; s_cur[tid] = 0; }
  __syncthreads();
  for (int i = tid; i < kT * kK; i += 256) {
    const int t = i >> 2, k = i & 3;
    const int e = ridx[i];
    bool last = true;
    for (int k2 = k + 1; k2 < kK; ++k2)
      if (ridx[t * kK + k2] == e) last = false;
    if (last) atomicAdd(&s_cnt[e], 1);
  }
  __syncthreads();
  if (tid == 0) {
    int acc = 0;
    for (int e = 0; e < kE; ++e) { s_off[e] = acc; acc += s_cnt[e]; }
    s_off[kE] = acc;
  }
  __syncthreads();
  if (tid <= kE) offs[tid] = s_off[tid];
  for (int i = tid; i < kT * kK; i += 256) {
    const int t = i >> 2, k = i & 3;
    const int e = ridx[i];
    bool last = true;
    for (int k2 = k + 1; k2 < kK; ++k2)
      if (ridx[t * kK + k2] == e) last = false;
    int g = -1;
    if (last) {
      const int p = atomicAdd(&s_cur[e], 1);
      g = s_off[e] + p;
      tok[g] = t;
      tw[g] = rw[i];
    }
    inv[i] = g;
  }
}

// ---------------------------------------------------------------------------
// hs fp32 -> fp16 pre-pass.
// ---------------------------------------------------------------------------
__global__ __launch_bounds__(256) void hs16_kernel(
    const float* __restrict__ hs, _Float16* __restrict__ hs16) {
  const size_t i = ((size_t)blockIdx.x * 256 + threadIdx.x) * 8;
  const float4v v0 = *(const float4v*)(hs + i);
  const float4v v1 = *(const float4v*)(hs + i + 4);
  half8 h;
  h[0] = (_Float16)v0[0]; h[1] = (_Float16)v0[1];
  h[2] = (_Float16)v0[2]; h[3] = (_Float16)v0[3];
  h[4] = (_Float16)v1[0]; h[5] = (_Float16)v1[1];
  h[6] = (_Float16)v1[2]; h[7] = (_Float16)v1[3];
  *(half8*)(hs16 + i) = h;
}

// ---------------------------------------------------------------------------
// Gate-up MFMA kernel, R4 "expert-persistent" form.
// Grid (32, 24): block = (expert e, 32 gate cols + paired 32 up cols).
// Block processes ALL tokens of its expert (320-row tile, loop for overflow)
// so each weight slice is fetched from HBM exactly once -> total weight
// fetch = 402 MB (optimal). linear%8 == e%8 keeps an expert on one XCD so
// its activation rows stay L2-resident across the 24 col-slice blocks.
// 4 waves split the 320 token rows (80 each, mt<5); all waves share cols.
// ---------------------------------------------------------------------------
__global__ __launch_bounds__(256) void gateup_kernel(
    const _Float16* __restrict__ hs16, const float* __restrict__ gup,
    const int* __restrict__ offs, const int* __restrict__ tok,
    _Float16* __restrict__ gated) {
  const int e  = blockIdx.x;        // 0..31
  const int i0 = blockIdx.y * 32;   // gate-col base (up col = kI + i0 + c)
  const int base = offs[e];
  const int Ne = offs[e + 1] - base;
  const int total = offs[kE];

  __shared__ _Float16 Asb[kTM * 40];  // [row][k], stride 40 halves
  __shared__ _Float16 Bsb[64 * 40];   // rows 0..31 gate, 32..63 up

  const int tid = threadIdx.x;
  // A staging: 5 units, row = (tid>>2) + 64*i, k-chunk (tid&3)*8
  const int arr = tid >> 2;
  const int akc = (tid & 3) * 8;
  // B staging: col c = tid&63 (gate if <32 else up), k-chunk (tid>>6)*8
  const int bc  = tid & 63;
  const int bk0 = (tid >> 6) * 8;
  const float* gupe = gup + (size_t)e * kH * (2 * kI);
  const size_t bcol = (bc < 32) ? (size_t)(i0 + bc)
                                : (size_t)(kI + i0 + (bc - 32));

  const int lane = tid & 63, wave = tid >> 6;
  const int m16 = lane & 15, quad = lane >> 4;

  for (int t0 = 0; t0 < Ne; t0 += kTM) {
    int arow[5];
#pragma unroll
    for (int i = 0; i < 5; ++i) {
      int slot = base + t0 + arr + 64 * i;
      slot = slot < total ? slot : total - 1;
      arow[i] = tok[slot] * kH;   // max ~4.2M, fits int
    }

    float4v accg[5][2], accu[5][2];
#pragma unroll
    for (int mt = 0; mt < 5; ++mt)
#pragma unroll
      for (int nt = 0; nt < 2; ++nt) {
        accg[mt][nt] = (float4v){0.f, 0.f, 0.f, 0.f};
        accu[mt][nt] = (float4v){0.f, 0.f, 0.f, 0.f};
      }

    half8 avA[5], avB[5];
    float bwA[8], bwB[8];

    auto gload = [&](int kk, half8 (&av)[5], float (&bw)[8]) {
#pragma unroll
      for (int i = 0; i < 5; ++i)
        av[i] = *(const half8*)(hs16 + arow[i] + kk + akc);
      const float* bp = gupe + (size_t)(kk + bk0) * (2 * kI) + bcol;
#pragma unroll
      for (int j = 0; j < 8; ++j)
        bw[j] = bp[(size_t)j * (2 * kI)];
    };

    auto lstore = [&](const half8 (&av)[5], const float (&bw)[8]) {
#pragma unroll
      for (int i = 0; i < 5; ++i)
        *(half8*)&Asb[(arr + 64 * i) * 40 + akc] = av[i];
      half8 h;
#pragma unroll
      for (int j = 0; j < 8; ++j) h[j] = (_Float16)bw[j];
      *(half8*)&Bsb[bc * 40 + bk0] = h;
    };

    auto compute = [&]() {
      half8 af[5], bfg[2], bfu[2];
#pragma unroll
      for (int mt = 0; mt < 5; ++mt)
        af[mt] =
            *(const half8*)&Asb[(wave * 80 + mt * 16 + m16) * 40 + quad * 8];
#pragma unroll
      for (int nt = 0; nt < 2; ++nt) {
        bfg[nt] = *(const half8*)&Bsb[(nt * 16 + m16) * 40 + quad * 8];
        bfu[nt] = *(const half8*)&Bsb[(32 + nt * 16 + m16) * 40 + quad * 8];
      }
#pragma unroll
      for (int mt = 0; mt < 5; ++mt)
#pragma unroll
        for (int nt = 0; nt < 2; ++nt) {
          accg[mt][nt] = __builtin_amdgcn_mfma_f32_16x16x32_f16(
              af[mt], bfg[nt], accg[mt][nt], 0, 0, 0);
          accu[mt][nt] = __builtin_amdgcn_mfma_f32_16x16x32_f16(
              af[mt], bfu[nt], accu[mt][nt], 0, 0, 0);
        }
    };

    gload(0, avA, bwA);
    for (int kk = 0; kk < kH; kk += 64) {
      __syncthreads();
      lstore(avA, bwA);
      gload(kk + 32, avB, bwB);
      __syncthreads();
      compute();
      __syncthreads();
      lstore(avB, bwB);
      if (kk + 64 < kH) gload(kk + 64, avA, bwA);
      __syncthreads();
      compute();
    }

    // epilogue: SwiGLU, store fp16 gated. D layout: row=quad*4+r, col=m16.
#pragma unroll
    for (int mt = 0; mt < 5; ++mt)
#pragma unroll
      for (int r = 0; r < 4; ++r) {
        const int rr = t0 + wave * 80 + mt * 16 + quad * 4 + r;
        if (rr < Ne) {
          _Float16* gp = gated + (size_t)(base + rr) * kI + i0;
#pragma unroll
          for (int nt = 0; nt < 2; ++nt) {
            const float g = accg[mt][nt][r];
            const float u = accu[mt][nt][r];
            gp[nt * 16 + m16] = (_Float16)(u * g / (1.f + expf(-g)));
          }
        }
      }
    __syncthreads();  // protect LDS before next t0 iteration (rare)
  }
}

// ---------------------------------------------------------------------------
// Down-proj MFMA kernel, R4 expert-persistent form.
// Grid (32, 32): block = (expert e, 64 H cols). Block processes all slots of
// its expert -> each weight slice fetched once (201 MB total, optimal).
// Epilogue: weighted plain stores into eo[slot][H].
// ---------------------------------------------------------------------------
__global__ __launch_bounds__(256) void down_kernel(
    const _Float16* __restrict__ gated, const float* __restrict__ dn,
    const int* __restrict__ offs, const int* __restrict__ tok,
    const float* __restrict__ tw, float* __restrict__ eo) {
  const int e  = blockIdx.x;        // 0..31
  const int h0 = blockIdx.y * 64;
  const int base = offs[e];
  const int Ne = offs[e + 1] - base;
  const int total = offs[kE];

  __shared__ _Float16 Asb[kTM * 40];
  __shared__ _Float16 Bsb[64 * 40];

  const int tid = threadIdx.x;
  const int arr = tid >> 2;         // + 64*i (i<5)
  const int akc = (tid & 3) * 8;
  const int bc  = tid & 63;         // h col within slice
  const int bk0 = (tid >> 6) * 8;
  const float* dne = dn + (size_t)e * kI * kH;

  const int lane = tid & 63, wave = tid >> 6;
  const int m16 = lane & 15, quad = lane >> 4;

  for (int t0 = 0; t0 < Ne; t0 += kTM) {
    int arow[5];
#pragma unroll
    for (int i = 0; i < 5; ++i) {
      int slot = base + t0 + arr + 64 * i;
      slot = slot < total ? slot : total - 1;
      arow[i] = slot * kI;   // max ~6.3M, fits int
    }

    float4v acc[5][4];
#pragma unroll
    for (int mt = 0; mt < 5; ++mt)
#pragma unroll
      for (int nt = 0; nt < 4; ++nt)
        acc[mt][nt] = (float4v){0.f, 0.f, 0.f, 0.f};

    half8 avA[5], avB[5];
    float bwA[8], bwB[8];

    auto gload = [&](int kk, half8 (&av)[5], float (&bw)[8]) {
#pragma unroll
      for (int i = 0; i < 5; ++i)
        av[i] = *(const half8*)(gated + arow[i] + kk + akc);
#pragma unroll
      for (int j = 0; j < 8; ++j)
        bw[j] = dne[(size_t)(kk + bk0 + j) * kH + h0 + bc];
    };

    auto lstore = [&](const half8 (&av)[5], const float (&bw)[8]) {
#pragma unroll
      for (int i = 0; i < 5; ++i)
        *(half8*)&Asb[(arr + 64 * i) * 40 + akc] = av[i];
      half8 h;
#pragma unroll
      for (int j = 0; j < 8; ++j) h[j] = (_Float16)bw[j];
      *(half8*)&Bsb[bc * 40 + bk0] = h;
    };

    auto compute = [&]() {
      half8 af[5], bf[4];
#pragma unroll
      for (int mt = 0; mt < 5; ++mt)
        af[mt] =
            *(const half8*)&Asb[(wave * 80 + mt * 16 + m16) * 40 + quad * 8];
#pragma unroll
      for (int nt = 0; nt < 4; ++nt)
        bf[nt] = *(const half8*)&Bsb[(nt * 16 + m16) * 40 + quad * 8];
#pragma unroll
      for (int mt = 0; mt < 5; ++mt)
#pragma unroll
        for (int nt = 0; nt < 4; ++nt)
          acc[mt][nt] = __builtin_amdgcn_mfma_f32_16x16x32_f16(
              af[mt], bf[nt], acc[mt][nt], 0, 0, 0);
    };

    gload(0, avA, bwA);
    for (int kk = 0; kk < kI; kk += 64) {
      __syncthreads();
      lstore(avA, bwA);
      gload(kk + 32, avB, bwB);
      __syncthreads();
      compute();
      __syncthreads();
      lstore(avB, bwB);
      if (kk + 64 < kI) gload(kk + 64, avA, bwA);
      __syncthreads();
      compute();
    }

    // epilogue: weighted plain stores into eo[slot][H]
#pragma unroll
    for (int mt = 0; mt < 5; ++mt)
#pragma unroll
      for (int r = 0; r < 4; ++r) {
        const int rr = t0 + wave * 80 + mt * 16 + quad * 4 + r;
        if (rr < Ne) {
          const int s = base + rr;
          const float w = tw[s];
          float* op = eo + (size_t)s * kH + h0;
#pragma unroll
          for (int nt = 0; nt < 4; ++nt)
            op[nt * 16 + m16] = acc[mt][nt][r] * w;
        }
      }
    __syncthreads();
  }
}

// ---------------------------------------------------------------------------
// Combine: out[t][:] = sum over this token's valid slots of eo[slot][:].
// ---------------------------------------------------------------------------
__global__ __launch_bounds__(256) void combine_kernel(
    const float* __restrict__ eo, const int* __restrict__ inv,
    float* __restrict__ out) {
  const int t = blockIdx.x;
  const int iv0 = inv[t * 4 + 0], iv1 = inv[t * 4 + 1];
  const int iv2 = inv[t * 4 + 2], iv3 = inv[t * 4 + 3];
  const int tid = threadIdx.x;
  for (int h = tid * 4; h < kH; h += 1024) {
    float4v a = (float4v){0.f, 0.f, 0.f, 0.f};
    if (iv0 >= 0) a += *(const float4v*)(eo + (size_t)iv0 * kH + h);
    if (iv1 >= 0) a += *(const float4v*)(eo + (size_t)iv1 * kH + h);
    if (iv2 >= 0) a += *(const float4v*)(eo + (size_t)iv2 * kH + h);
    if (iv3 >= 0) a += *(const float4v*)(eo + (size_t)iv3 * kH + h);
    *(float4v*)(out + (size_t)t * kH + h) = a;
  }
}

extern "C" void kernel_launch(void* const* d_in, const int* in_sizes, int n_in,
                              void* d_out, int out_size, void* d_ws, size_t ws_size,
                              hipStream_t stream) {
  const float* hs   = (const float*)d_in[0];
  const float* rw   = (const float*)d_in[1];
  const int*   ridx = (const int*)d_in[2];
  const float* gup  = (const float*)d_in[4];
  const float* dn   = (const float*)d_in[5];
  float* out = (float*)d_out;

  char* ws = (char*)d_ws;
  int*      offs  = (int*)(ws + kOffsOff);
  int*      tok   = (int*)(ws + kTokOff);
  float*    tw    = (float*)(ws + kTwOff);
  int*      inv   = (int*)(ws + kInvOff);
  _Float16* gated = (_Float16*)(ws + kGatedOff);
  float*    eo    = (float*)(ws + kEoOff);
  _Float16* hs16  = (_Float16*)(ws + kHs16Off);

  route_kernel<<<1, 256, 0, stream>>>(ridx, rw, offs, tok, tw, inv);
  hs16_kernel<<<(kT * kH) / (256 * 8), 256, 0, stream>>>(hs, hs16);
  gateup_kernel<<<dim3(kE, kI / 32), 256, 0, stream>>>(hs16, gup, offs, tok, gated);
  down_kernel<<<dim3(kE, kH / 64), 256, 0, stream>>>(gated, dn, offs, tok, tw, eo);
  combine_kernel<<<kT, 256, 0, stream>>>(eo, inv, out);
}